// Round 7
// baseline (253.622 us; speedup 1.0000x reference)
//
#include <hip/hip_runtime.h>
#include <hip/hip_fp16.h>

#define D 128
#define EPS 1e-5f
#define EPB 16384      // edges per counting/scatter block
#define NBSH 7         // bucket = dst >> NBSH
#define BUCKW 128      // dsts per bucket

typedef unsigned int u32;
typedef unsigned short u16;
typedef __attribute__((ext_vector_type(8))) _Float16 half8;  // mfma A/B frag
typedef __attribute__((ext_vector_type(4))) float f32x4;

__device__ inline u16 f2h(float x) {
  _Float16 t = (_Float16)x;
  return __builtin_bit_cast(u16, t);
}
__device__ inline __half2 b2h2(u32 u) { return __builtin_bit_cast(__half2, u); }

// ---------------------------------------------------------------------------
// P0: convert W1,W2 fp32[k][c] -> fp16 Wt[c][k]. (No zero-init needed: the
// sort pipeline writes every cell it reads.)
__global__ __launch_bounds__(256) void k_prep(const float* __restrict__ W1,
                                              const float* __restrict__ W2,
                                              u16* __restrict__ Wt1,
                                              u16* __restrict__ Wt2) {
  int i = blockIdx.x * 256 + threadIdx.x;
  if (i < 2 * D * D) {
    const float* W = (i < D * D) ? W1 : W2;
    u16* Wt = (i < D * D) ? Wt1 : Wt2;
    int ii = i & (D * D - 1);
    int k = ii >> 7, c = ii & 127;
    Wt[c * D + k] = f2h(W[ii]);
  }
}

// ---------------------------------------------------------------------------
// LDS-free MFMA GEMM body: out[r,:] = fp16( in[r,:] @ W ), 64 rows per block.
// A-frag: lane(m,q) = A[row0+m][k=q*8+j] (contiguous 16B). B from Wt[c][k]
// (L2-hot 32KB). D-layout: col = ct*16 + (lane&15), row = quad*4 + reg.
template <bool F32IN>
__device__ __forceinline__ void gemm_body(const void* __restrict__ in_,
                                          const u16* __restrict__ Wt,
                                          u16* __restrict__ out, int nrows,
                                          int blk) {
  const int tid = threadIdx.x;
  const int lane = tid & 63, wv = tid >> 6;
  const int m = lane & 15, q = lane >> 4;
  const int r0 = blk * 64 + wv * 16;
  const int rowa = min(r0 + m, nrows - 1);

  f32x4 acc[8];
#pragma unroll
  for (int ct = 0; ct < 8; ct++) acc[ct] = (f32x4)(0.0f);

#pragma unroll
  for (int kk = 0; kk < 4; kk++) {
    const int kbase = kk * 32 + q * 8;
    half8 a;
    if (F32IN) {
      const float* in = (const float*)in_;
      float4 v0 = *(const float4*)(in + (size_t)rowa * D + kbase);
      float4 v1 = *(const float4*)(in + (size_t)rowa * D + kbase + 4);
      a[0] = (_Float16)v0.x; a[1] = (_Float16)v0.y;
      a[2] = (_Float16)v0.z; a[3] = (_Float16)v0.w;
      a[4] = (_Float16)v1.x; a[5] = (_Float16)v1.y;
      a[6] = (_Float16)v1.z; a[7] = (_Float16)v1.w;
    } else {
      const u16* in = (const u16*)in_;
      a = *(const half8*)(in + (size_t)rowa * D + kbase);
    }
#pragma unroll
    for (int ct = 0; ct < 8; ct++) {
      half8 b = *(const half8*)(Wt + (ct * 16 + m) * D + kbase);
      acc[ct] = __builtin_amdgcn_mfma_f32_16x16x32_f16(a, b, acc[ct], 0, 0, 0);
    }
  }

#pragma unroll
  for (int ct = 0; ct < 8; ct++) {
#pragma unroll
    for (int rg = 0; rg < 4; rg++) {
      int rr = r0 + q * 4 + rg;
      if (rr < nrows) out[(size_t)rr * D + ct * 16 + m] = f2h(acc[ct][rg]);
    }
  }
}

// S1: coarse-bucket count (blocks [0,KB), LDS atomics only) || GEMM1.
__global__ __launch_bounds__(256) void k_count_gemm1(
    const int* __restrict__ dst, int* __restrict__ cnt, int E, int KB, int NB,
    const float* __restrict__ x, const u16* __restrict__ Wt1,
    u16* __restrict__ A, int nrows) {
  __shared__ int hist[512];
  if (blockIdx.x < (u32)KB) {
    int k = blockIdx.x;
    for (int i = threadIdx.x; i < NB; i += 256) hist[i] = 0;
    __syncthreads();
    int e0 = k * EPB, e1 = min(E, e0 + EPB);
    for (int e = e0 + threadIdx.x; e < e1; e += 256)
      atomicAdd(&hist[dst[e] >> NBSH], 1);
    __syncthreads();
    for (int b = threadIdx.x; b < NB; b += 256)
      cnt[b * KB + k] = hist[b];   // bucket-major
  } else {
    gemm_body<true>(x, Wt1, A, nrows, blockIdx.x - KB);
  }
}

// S2: single-block exclusive scan over cnt[M] (bucket-major), in place.
// Also emits bs[b] = bucket start, bs[NB] = E.
__global__ __launch_bounds__(1024) void k_scan(int* __restrict__ cnt, int M,
                                               int KB, int NB,
                                               int* __restrict__ bs, int E) {
  __shared__ int wt[16];
  const int tid = threadIdx.x;
  const int lane = tid & 63, wid = tid >> 6;
  int running = 0;
  int chunks = (M + 1023) >> 10;
  for (int c = 0; c < chunks; c++) {
    int i = (c << 10) + tid;
    int v = (i < M) ? cnt[i] : 0;
    int incl = v;
#pragma unroll
    for (int o = 1; o < 64; o <<= 1) {
      int t = __shfl_up(incl, o, 64);
      if (lane >= o) incl += t;
    }
    if (lane == 63) wt[wid] = incl;
    __syncthreads();
    int woff = 0, total = 0;
#pragma unroll
    for (int j = 0; j < 16; j++) {
      int t = wt[j];
      if (j < wid) woff += t;
      total += t;
    }
    int excl = running + woff + incl - v;
    if (i < M) {
      cnt[i] = excl;
      if (i - (i / KB) * KB == 0) bs[i / KB] = excl;
    }
    running += total;
    __syncthreads();
  }
  if (tid == 0) bs[NB] = E;
}

// S3: scatter edges into bucket-grouped tmp. Ranks via LDS atomics against
// the scanned (bucket, block) bases. tmp entry = src:16 | dstlow:7.
__global__ __launch_bounds__(256) void k_scatter_bins(
    const int* __restrict__ src, const int* __restrict__ dst,
    const int* __restrict__ base, int E, int KB, int NB,
    u32* __restrict__ tmp) {
  __shared__ int off[512];
  int k = blockIdx.x;
  for (int b = threadIdx.x; b < NB; b += 256) off[b] = base[b * KB + k];
  __syncthreads();
  int e0 = k * EPB, e1 = min(E, e0 + EPB);
  for (int e = e0 + threadIdx.x; e < e1; e += 256) {
    int d = dst[e], s = src[e];
    int p = atomicAdd(&off[d >> NBSH], 1);
    tmp[p] = (u32)s | ((u32)(d & (BUCKW - 1)) << 16);
  }
}

// S4: one block per bucket. 128-bin LDS histogram + scan -> per-node deg /
// dinv / meta, and dst-sorted csr (coalesced writes). No global atomics.
__global__ __launch_bounds__(256) void k_bucket_csr(
    const u32* __restrict__ tmp, const int* __restrict__ bs,
    int4* __restrict__ meta, float* __restrict__ dinv,
    u32* __restrict__ csr, int N) {
  __shared__ int hist[BUCKW];
  __shared__ int sc[BUCKW];
  __shared__ int off[BUCKW];
  const int b = blockIdx.x;
  const int tid = threadIdx.x;
  const int s0 = bs[b], s1 = bs[b + 1];
  if (tid < BUCKW) hist[tid] = 0;
  __syncthreads();
  for (int i = s0 + tid; i < s1; i += 256)
    atomicAdd(&hist[(tmp[i] >> 16) & (BUCKW - 1)], 1);
  __syncthreads();
  if (tid < BUCKW) sc[tid] = hist[tid];
  __syncthreads();
#pragma unroll
  for (int o = 1; o < BUCKW; o <<= 1) {
    int t = 0;
    if (tid < BUCKW && tid >= o) t = sc[tid - o];
    __syncthreads();
    if (tid < BUCKW) sc[tid] += t;
    __syncthreads();
  }
  if (tid < BUCKW) {
    int excl = sc[tid] - hist[tid];      // exclusive within bucket
    off[tid] = excl;
    int d = b * BUCKW + tid;
    if (d < N) {
      int dg = hist[tid];
      float dv = rsqrtf((float)dg + 1.0f);
      meta[d] = make_int4(s0 + excl, dg, __builtin_bit_cast(int, dv), 0);
      dinv[d] = dv;
    }
  }
  __syncthreads();
  for (int i = s0 + tid; i < s1; i += 256) {
    u32 t = tmp[i];
    int l = (t >> 16) & (BUCKW - 1);
    int r = atomicAdd(&off[l], 1);       // LDS
    csr[s0 + r] = t;
  }
}

// S5: pack weights: csr entry src:16|dstlow -> src:16 | fp16(dinv[s]*dinv[d]).
__global__ __launch_bounds__(256) void k_weights(
    const int4* __restrict__ meta, const float* __restrict__ dinv,
    u32* __restrict__ csr, int N) {
  int r = blockIdx.x * 256 + threadIdx.x;
  if (r >= N) return;
  int4 mt = meta[r];
  int st = mt.x, dg = mt.y;
  float dv = __builtin_bit_cast(float, mt.z);
  for (int j = 0; j < dg; j++) {
    u32 t = csr[st + j];
    u32 s = t & 0xffffu;
    float w = dinv[s] * dv;
    csr[st + j] = s | ((u32)f2h(w) << 16);
  }
}

// P7: standalone GEMM2 (fp16 input).
__global__ __launch_bounds__(256) void k_gemm2(const u16* __restrict__ in,
                                               const u16* __restrict__ Wt,
                                               u16* __restrict__ out, int nrows) {
  gemm_body<false>(in, Wt, out, nrows, blockIdx.x);
}

// ---------------------------------------------------------------------------
// Fused CSR gather (fp16 h) + self-loop + bias + LN + ReLU (+residual).
// 4 rows per wave: 16 lanes per row, uint4 (8 fp16) per lane covers the 256B
// row. Unroll-4 => 16 edge-row loads in flight per wave. Branch-free body:
// padded entries are e=0 (src 0, w +0).
__global__ __launch_bounds__(256) void k_gather_ln(
    const uint4* __restrict__ hb, const int4* __restrict__ meta,
    const u32* __restrict__ csr,
    const float* __restrict__ b, const float* __restrict__ g,
    const float* __restrict__ bln, const float* __restrict__ resid,
    float* __restrict__ outf, uint4* __restrict__ outb, int n) {
  const int tid = threadIdx.x;
  const int sl = tid & 15;                     // lane within row-group
  const int row = blockIdx.x * 16 + (tid >> 4);
  const bool valid = row < n;
  const int rc = valid ? row : 0;

  int4 mt = meta[rc];
  int beg = mt.x;
  int cnt = valid ? mt.y : 0;
  float dv = __builtin_bit_cast(float, mt.z);
  __half2 sn2 = __float2half2_rn(dv * dv);

  uint4 su = hb[(size_t)rc * 16 + sl];
  __half2 acc0 = __hmul2(b2h2(su.x), sn2);
  __half2 acc1 = __hmul2(b2h2(su.y), sn2);
  __half2 acc2 = __hmul2(b2h2(su.z), sn2);
  __half2 acc3 = __hmul2(b2h2(su.w), sn2);

  int cm = max(cnt, __shfl_xor(cnt, 16, 64));
  cm = max(cm, __shfl_xor(cm, 32, 64));

  for (int j0 = 0; j0 < cm; j0 += 16) {
    u32 e = 0u;
    if (sl < cnt - j0) e = csr[beg + j0 + sl];  // lanes past cnt hold e=0
    int mm = min(cm - j0, 16);
    for (int j = 0; j < mm; j += 4) {
      u32 e0 = __shfl(e, j, 16),     e1 = __shfl(e, j + 1, 16);
      u32 e2 = __shfl(e, j + 2, 16), e3 = __shfl(e, j + 3, 16);
      uint4 v0 = hb[(size_t)(e0 & 0xffffu) * 16 + sl];
      uint4 v1 = hb[(size_t)(e1 & 0xffffu) * 16 + sl];
      uint4 v2 = hb[(size_t)(e2 & 0xffffu) * 16 + sl];
      uint4 v3 = hb[(size_t)(e3 & 0xffffu) * 16 + sl];
      __half2 w0 = b2h2((e0 >> 16) | (e0 & 0xffff0000u));
      __half2 w1 = b2h2((e1 >> 16) | (e1 & 0xffff0000u));
      __half2 w2 = b2h2((e2 >> 16) | (e2 & 0xffff0000u));
      __half2 w3 = b2h2((e3 >> 16) | (e3 & 0xffff0000u));
      acc0 = __hfma2(b2h2(v0.x), w0, acc0);
      acc1 = __hfma2(b2h2(v0.y), w0, acc1);
      acc2 = __hfma2(b2h2(v0.z), w0, acc2);
      acc3 = __hfma2(b2h2(v0.w), w0, acc3);
      acc0 = __hfma2(b2h2(v1.x), w1, acc0);
      acc1 = __hfma2(b2h2(v1.y), w1, acc1);
      acc2 = __hfma2(b2h2(v1.z), w1, acc2);
      acc3 = __hfma2(b2h2(v1.w), w1, acc3);
      acc0 = __hfma2(b2h2(v2.x), w2, acc0);
      acc1 = __hfma2(b2h2(v2.y), w2, acc1);
      acc2 = __hfma2(b2h2(v2.z), w2, acc2);
      acc3 = __hfma2(b2h2(v2.w), w2, acc3);
      acc0 = __hfma2(b2h2(v3.x), w3, acc0);
      acc1 = __hfma2(b2h2(v3.y), w3, acc1);
      acc2 = __hfma2(b2h2(v3.z), w3, acc2);
      acc3 = __hfma2(b2h2(v3.w), w3, acc3);
    }
  }

  // ---- LayerNorm over 128 cols, 8 per lane across 16 lanes ----
  float2 f0 = __half22float2(acc0);
  float2 f1 = __half22float2(acc1);
  float2 f2 = __half22float2(acc2);
  float2 f3 = __half22float2(acc3);
  int d0 = sl * 8;
  float4 bb0 = *(const float4*)(b + d0);
  float4 bb1 = *(const float4*)(b + d0 + 4);
  float a0 = f0.x + bb0.x, a1 = f0.y + bb0.y;
  float a2 = f1.x + bb0.z, a3 = f1.y + bb0.w;
  float a4 = f2.x + bb1.x, a5 = f2.y + bb1.y;
  float a6 = f3.x + bb1.z, a7 = f3.y + bb1.w;

  float sum = ((a0 + a1) + (a2 + a3)) + ((a4 + a5) + (a6 + a7));
#pragma unroll
  for (int o = 8; o >= 1; o >>= 1) sum += __shfl_xor(sum, o, 16);
  float mu = sum * (1.0f / 128.0f);
  float e0 = a0 - mu, e1 = a1 - mu, e2 = a2 - mu, e3 = a3 - mu;
  float e4 = a4 - mu, e5 = a5 - mu, e6 = a6 - mu, e7 = a7 - mu;
  float vs = ((e0 * e0 + e1 * e1) + (e2 * e2 + e3 * e3)) +
             ((e4 * e4 + e5 * e5) + (e6 * e6 + e7 * e7));
#pragma unroll
  for (int o = 8; o >= 1; o >>= 1) vs += __shfl_xor(vs, o, 16);
  float inv = rsqrtf(vs * (1.0f / 128.0f) + EPS);

  float4 gg0 = *(const float4*)(g + d0);
  float4 gg1 = *(const float4*)(g + d0 + 4);
  float4 bl0 = *(const float4*)(bln + d0);
  float4 bl1 = *(const float4*)(bln + d0 + 4);
  float o0 = fmaxf(e0 * inv * gg0.x + bl0.x, 0.0f);
  float o1 = fmaxf(e1 * inv * gg0.y + bl0.y, 0.0f);
  float o2 = fmaxf(e2 * inv * gg0.z + bl0.z, 0.0f);
  float o3 = fmaxf(e3 * inv * gg0.w + bl0.w, 0.0f);
  float o4 = fmaxf(e4 * inv * gg1.x + bl1.x, 0.0f);
  float o5 = fmaxf(e5 * inv * gg1.y + bl1.y, 0.0f);
  float o6 = fmaxf(e6 * inv * gg1.z + bl1.z, 0.0f);
  float o7 = fmaxf(e7 * inv * gg1.w + bl1.w, 0.0f);

  if (!valid) return;
  if (outb) {
    uint4 pk;
    pk.x = ((u32)f2h(o1) << 16) | (u32)f2h(o0);
    pk.y = ((u32)f2h(o3) << 16) | (u32)f2h(o2);
    pk.z = ((u32)f2h(o5) << 16) | (u32)f2h(o4);
    pk.w = ((u32)f2h(o7) << 16) | (u32)f2h(o6);
    outb[(size_t)row * 16 + sl] = pk;
  } else {
    size_t base = (size_t)row * D + d0;
    float4 r0 = *(const float4*)(resid + base);
    float4 r1 = *(const float4*)(resid + base + 4);
    *(float4*)(outf + base) =
        make_float4(o0 + r0.x, o1 + r0.y, o2 + r0.z, o3 + r0.w);
    *(float4*)(outf + base + 4) =
        make_float4(o4 + r1.x, o5 + r1.y, o6 + r1.z, o7 + r1.w);
  }
}

// ---------------------------------------------------------------------------
extern "C" void kernel_launch(void* const* d_in, const int* in_sizes, int n_in,
                              void* d_out, int out_size, void* d_ws, size_t ws_size,
                              hipStream_t stream) {
  const float* x    = (const float*)d_in[0];
  const int*   ei   = (const int*)d_in[1];
  const float* W1   = (const float*)d_in[2];
  const float* b1   = (const float*)d_in[3];
  const float* g1   = (const float*)d_in[4];
  const float* bl1  = (const float*)d_in[5];
  const float* W2   = (const float*)d_in[6];
  const float* b2   = (const float*)d_in[7];
  const float* g2   = (const float*)d_in[8];
  const float* bl2  = (const float*)d_in[9];

  const int N = in_sizes[0] / D;
  const int E = in_sizes[1] / 2;
  const int* src = ei;
  const int* dst = ei + E;

  const int NB = (N + BUCKW - 1) / BUCKW;   // coarse buckets
  const int KB = (E + EPB - 1) / EPB;       // counting blocks
  const int M  = NB * KB;
  const int GB = (N + 63) / 64;             // gemm blocks

  size_t off = 0;
  auto walloc = [&](size_t bytes) {
    void* p = (char*)d_ws + off;
    off = (off + bytes + 255) & ~(size_t)255;
    return p;
  };
  int*   cnt   = (int*)walloc((size_t)M * 4);
  int*   bs    = (int*)walloc((size_t)(NB + 1) * 4);
  u32*   tmp   = (u32*)walloc((size_t)E * 4);
  u32*   csr   = (u32*)walloc((size_t)E * 4);
  int4*  meta  = (int4*)walloc((size_t)N * 16);
  float* dinv  = (float*)walloc((size_t)N * 4);
  u16*   A     = (u16*)walloc((size_t)N * D * 2);   // h (fp16)
  u16*   B     = (u16*)walloc((size_t)N * D * 2);   // y1 (fp16)
  u16*   Wt1   = (u16*)walloc((size_t)D * D * 2);
  u16*   Wt2   = (u16*)walloc((size_t)D * D * 2);
  float* O     = (float*)d_out;

  // P0: weight converts
  k_prep<<<(2 * D * D + 255) / 256, 256, 0, stream>>>(W1, W2, Wt1, Wt2);
  // S1: coarse count || GEMM1 (x @ W1 -> A)
  k_count_gemm1<<<KB + GB, 256, 0, stream>>>(dst, cnt, E, KB, NB, x, Wt1, A, N);
  // S2: scan
  k_scan<<<1, 1024, 0, stream>>>(cnt, M, KB, NB, bs, E);
  // S3: scatter into buckets
  k_scatter_bins<<<KB, 256, 0, stream>>>(src, dst, cnt, E, KB, NB, tmp);
  // S4: per-bucket sort -> csr + meta + dinv
  k_bucket_csr<<<NB, 256, 0, stream>>>(tmp, bs, meta, dinv, csr, N);
  // S5: pack edge weights
  k_weights<<<(N + 255) / 256, 256, 0, stream>>>(meta, dinv, csr, N);
  // P6: gather + LN + ReLU -> B (fp16)
  k_gather_ln<<<(N + 15) / 16, 256, 0, stream>>>((const uint4*)A, meta, csr,
                                                 b1, g1, bl1, nullptr,
                                                 nullptr, (uint4*)B, N);
  // P7: GEMM2 (B @ W2 -> A)
  k_gemm2<<<GB, 256, 0, stream>>>(B, Wt2, A, N);
  // P8: gather + LN + ReLU + residual -> O (fp32)
  k_gather_ln<<<(N + 15) / 16, 256, 0, stream>>>((const uint4*)A, meta, csr,
                                                 b2, g2, bl2, x,
                                                 O, nullptr, N);
}

// Round 8
// 224.838 us; speedup vs baseline: 1.1280x; 1.1280x over previous
//
#include <hip/hip_runtime.h>
#include <hip/hip_fp16.h>

#define D 128
#define EPS 1e-5f

typedef unsigned int u32;
typedef unsigned short u16;
typedef __attribute__((ext_vector_type(8))) _Float16 half8;  // mfma A/B frag
typedef __attribute__((ext_vector_type(4))) float f32x4;

__device__ inline u16 f2h(float x) {
  _Float16 t = (_Float16)x;
  return __builtin_bit_cast(u16, t);
}
__device__ inline __half2 b2h2(u32 u) { return __builtin_bit_cast(__half2, u); }

// ---------------------------------------------------------------------------
// P0: zero counter, convert W1,W2 fp32[k][c] -> fp16 Wt[c][k].
__global__ __launch_bounds__(256) void k_prep(const float* __restrict__ W1,
                                              const float* __restrict__ W2,
                                              u16* __restrict__ Wt1,
                                              u16* __restrict__ Wt2,
                                              int* __restrict__ deg,
                                              int* __restrict__ counter, int n) {
  int i = blockIdx.x * 256 + threadIdx.x;
  if (i < n) deg[i] = 0;
  if (i == 0) *counter = 0;
  if (i < 2 * D * D) {
    const float* W = (i < D * D) ? W1 : W2;
    u16* Wt = (i < D * D) ? Wt1 : Wt2;
    int ii = i & (D * D - 1);
    int k = ii >> 7, c = ii & 127;
    Wt[c * D + k] = f2h(W[ii]);
  }
}

// ---------------------------------------------------------------------------
// LDS-free MFMA GEMM body (global A). See R6 comments.
template <bool F32IN>
__device__ __forceinline__ void gemm_body(const void* __restrict__ in_,
                                          const u16* __restrict__ Wt,
                                          u16* __restrict__ out, int nrows,
                                          int blk) {
  const int tid = threadIdx.x;
  const int lane = tid & 63, wv = tid >> 6;
  const int m = lane & 15, q = lane >> 4;
  const int r0 = blk * 64 + wv * 16;
  const int rowa = min(r0 + m, nrows - 1);

  f32x4 acc[8];
#pragma unroll
  for (int ct = 0; ct < 8; ct++) acc[ct] = (f32x4)(0.0f);

#pragma unroll
  for (int kk = 0; kk < 4; kk++) {
    const int kbase = kk * 32 + q * 8;
    half8 a;
    if (F32IN) {
      const float* in = (const float*)in_;
      float4 v0 = *(const float4*)(in + (size_t)rowa * D + kbase);
      float4 v1 = *(const float4*)(in + (size_t)rowa * D + kbase + 4);
      a[0] = (_Float16)v0.x; a[1] = (_Float16)v0.y;
      a[2] = (_Float16)v0.z; a[3] = (_Float16)v0.w;
      a[4] = (_Float16)v1.x; a[5] = (_Float16)v1.y;
      a[6] = (_Float16)v1.z; a[7] = (_Float16)v1.w;
    } else {
      const u16* in = (const u16*)in_;
      a = *(const half8*)(in + (size_t)rowa * D + kbase);
    }
#pragma unroll
    for (int ct = 0; ct < 8; ct++) {
      half8 b = *(const half8*)(Wt + (ct * 16 + m) * D + kbase);
      acc[ct] = __builtin_amdgcn_mfma_f32_16x16x32_f16(a, b, acc[ct], 0, 0, 0);
    }
  }

#pragma unroll
  for (int ct = 0; ct < 8; ct++) {
#pragma unroll
    for (int rg = 0; rg < 4; rg++) {
      int rr = r0 + q * 4 + rg;
      if (rr < nrows) out[(size_t)rr * D + ct * 16 + m] = f2h(acc[ct][rg]);
    }
  }
}

// P1: deg histogram + per-edge rank, 4 edges/thread for atomic MLP
// (blocks [0,DB)) || GEMM1 (blocks >= DB).
__global__ __launch_bounds__(256) void k_deg_gemm1(
    const int* __restrict__ dst, int* __restrict__ deg, int* __restrict__ rank,
    int E, int DB,
    const float* __restrict__ x, const u16* __restrict__ Wt1,
    u16* __restrict__ A, int nrows) {
  if (blockIdx.x < (u32)DB) {
    int base = blockIdx.x * 1024 + threadIdx.x;
    int e0 = base, e1 = base + 256, e2 = base + 512, e3 = base + 768;
    int d0 = (e0 < E) ? dst[e0] : 0;
    int d1 = (e1 < E) ? dst[e1] : 0;
    int d2 = (e2 < E) ? dst[e2] : 0;
    int d3 = (e3 < E) ? dst[e3] : 0;
    int r0 = 0, r1 = 0, r2 = 0, r3 = 0;
    if (e0 < E) r0 = atomicAdd(&deg[d0], 1);
    if (e1 < E) r1 = atomicAdd(&deg[d1], 1);
    if (e2 < E) r2 = atomicAdd(&deg[d2], 1);
    if (e3 < E) r3 = atomicAdd(&deg[d3], 1);
    if (e0 < E) rank[e0] = r0;
    if (e1 < E) rank[e1] = r1;
    if (e2 < E) rank[e2] = r2;
    if (e3 < E) rank[e3] = r3;
  } else {
    gemm_body<true>(x, Wt1, A, nrows, blockIdx.x - DB);
  }
}

// P2: dinv + CSR range alloc; meta[i] = {start, deg, dinv_bits, 0}.
__global__ __launch_bounds__(256) void k_alloc(const int* __restrict__ deg,
                                               float* __restrict__ dinv,
                                               int4* __restrict__ meta,
                                               int* __restrict__ counter, int n) {
  int i = blockIdx.x * 256 + threadIdx.x;
  int lane = threadIdx.x & 63;
  int d = (i < n) ? deg[i] : 0;
  float dv = rsqrtf((float)d + 1.0f);
  int v = d;
#pragma unroll
  for (int o = 1; o < 64; o <<= 1) {
    int t = __shfl_up(v, o, 64);
    if (lane >= o) v += t;
  }
  int total = __shfl(v, 63, 64);
  int base = 0;
  if (lane == 0) base = atomicAdd(counter, total);
  base = __shfl(base, 0, 64);
  if (i < n) {
    int st = base + v - d;
    dinv[i] = dv;
    meta[i] = make_int4(st, d, __builtin_bit_cast(int, dv), 0);
  }
}

// P3: CSR fill, atomic-free, 4 edges/thread for load MLP.
// pos = meta[d].start + rank[e]; w = dinv[s] * meta[d].dinv.
__global__ __launch_bounds__(256) void k_fill(
    const int* __restrict__ src, const int* __restrict__ dst,
    const int* __restrict__ rank, const int4* __restrict__ meta,
    const float* __restrict__ dinv, u32* __restrict__ csr, int E) {
  int base = blockIdx.x * 1024 + threadIdx.x;
#pragma unroll
  for (int t = 0; t < 4; t++) {
    int e = base + t * 256;
    if (e < E) {
      int s = src[e], d = dst[e];
      int4 mt = meta[d];
      float w = dinv[s] * __builtin_bit_cast(float, mt.z);
      csr[mt.x + rank[e]] = (u32)s | ((u32)f2h(w) << 16);
    }
  }
}

// ---------------------------------------------------------------------------
// Gather+LN core: computes LN(relu-free) outputs o0..o7 for `row`, lane sl
// owning cols sl*8..sl*8+7. Returns via reference args.
__device__ __forceinline__ void gather_ln_core(
    const uint4* __restrict__ hb, const int4* __restrict__ meta,
    const u32* __restrict__ csr, const float* __restrict__ b,
    const float* __restrict__ g, const float* __restrict__ bln,
    int row, int n, int sl, float out[8]) {
  const bool valid = row < n;
  const int rc = valid ? row : 0;
  int4 mt = meta[rc];
  int beg = mt.x;
  int cnt = valid ? mt.y : 0;
  float dv = __builtin_bit_cast(float, mt.z);
  __half2 sn2 = __float2half2_rn(dv * dv);

  uint4 su = hb[(size_t)rc * 16 + sl];
  __half2 acc0 = __hmul2(b2h2(su.x), sn2);
  __half2 acc1 = __hmul2(b2h2(su.y), sn2);
  __half2 acc2 = __hmul2(b2h2(su.z), sn2);
  __half2 acc3 = __hmul2(b2h2(su.w), sn2);

  int cm = max(cnt, __shfl_xor(cnt, 16, 64));
  cm = max(cm, __shfl_xor(cm, 32, 64));

  for (int j0 = 0; j0 < cm; j0 += 16) {
    u32 e = 0u;
    if (sl < cnt - j0) e = csr[beg + j0 + sl];
    int mm = min(cm - j0, 16);
    for (int j = 0; j < mm; j += 4) {
      u32 e0 = __shfl(e, j, 16),     e1 = __shfl(e, j + 1, 16);
      u32 e2 = __shfl(e, j + 2, 16), e3 = __shfl(e, j + 3, 16);
      uint4 v0 = hb[(size_t)(e0 & 0xffffu) * 16 + sl];
      uint4 v1 = hb[(size_t)(e1 & 0xffffu) * 16 + sl];
      uint4 v2 = hb[(size_t)(e2 & 0xffffu) * 16 + sl];
      uint4 v3 = hb[(size_t)(e3 & 0xffffu) * 16 + sl];
      __half2 w0 = b2h2((e0 >> 16) | (e0 & 0xffff0000u));
      __half2 w1 = b2h2((e1 >> 16) | (e1 & 0xffff0000u));
      __half2 w2 = b2h2((e2 >> 16) | (e2 & 0xffff0000u));
      __half2 w3 = b2h2((e3 >> 16) | (e3 & 0xffff0000u));
      acc0 = __hfma2(b2h2(v0.x), w0, acc0);
      acc1 = __hfma2(b2h2(v0.y), w0, acc1);
      acc2 = __hfma2(b2h2(v0.z), w0, acc2);
      acc3 = __hfma2(b2h2(v0.w), w0, acc3);
      acc0 = __hfma2(b2h2(v1.x), w1, acc0);
      acc1 = __hfma2(b2h2(v1.y), w1, acc1);
      acc2 = __hfma2(b2h2(v1.z), w1, acc2);
      acc3 = __hfma2(b2h2(v1.w), w1, acc3);
      acc0 = __hfma2(b2h2(v2.x), w2, acc0);
      acc1 = __hfma2(b2h2(v2.y), w2, acc1);
      acc2 = __hfma2(b2h2(v2.z), w2, acc2);
      acc3 = __hfma2(b2h2(v2.w), w2, acc3);
      acc0 = __hfma2(b2h2(v3.x), w3, acc0);
      acc1 = __hfma2(b2h2(v3.y), w3, acc1);
      acc2 = __hfma2(b2h2(v3.z), w3, acc2);
      acc3 = __hfma2(b2h2(v3.w), w3, acc3);
    }
  }

  float2 f0 = __half22float2(acc0);
  float2 f1 = __half22float2(acc1);
  float2 f2 = __half22float2(acc2);
  float2 f3 = __half22float2(acc3);
  int d0 = sl * 8;
  float4 bb0 = *(const float4*)(b + d0);
  float4 bb1 = *(const float4*)(b + d0 + 4);
  float a0 = f0.x + bb0.x, a1 = f0.y + bb0.y;
  float a2 = f1.x + bb0.z, a3 = f1.y + bb0.w;
  float a4 = f2.x + bb1.x, a5 = f2.y + bb1.y;
  float a6 = f3.x + bb1.z, a7 = f3.y + bb1.w;

  float sum = ((a0 + a1) + (a2 + a3)) + ((a4 + a5) + (a6 + a7));
#pragma unroll
  for (int o = 8; o >= 1; o >>= 1) sum += __shfl_xor(sum, o, 16);
  float mu = sum * (1.0f / 128.0f);
  float e0 = a0 - mu, e1 = a1 - mu, e2 = a2 - mu, e3 = a3 - mu;
  float e4 = a4 - mu, e5 = a5 - mu, e6 = a6 - mu, e7 = a7 - mu;
  float vs = ((e0 * e0 + e1 * e1) + (e2 * e2 + e3 * e3)) +
             ((e4 * e4 + e5 * e5) + (e6 * e6 + e7 * e7));
#pragma unroll
  for (int o = 8; o >= 1; o >>= 1) vs += __shfl_xor(vs, o, 16);
  float inv = rsqrtf(vs * (1.0f / 128.0f) + EPS);

  float4 gg0 = *(const float4*)(g + d0);
  float4 gg1 = *(const float4*)(g + d0 + 4);
  float4 bl0 = *(const float4*)(bln + d0);
  float4 bl1 = *(const float4*)(bln + d0 + 4);
  out[0] = fmaxf(e0 * inv * gg0.x + bl0.x, 0.0f);
  out[1] = fmaxf(e1 * inv * gg0.y + bl0.y, 0.0f);
  out[2] = fmaxf(e2 * inv * gg0.z + bl0.z, 0.0f);
  out[3] = fmaxf(e3 * inv * gg0.w + bl0.w, 0.0f);
  out[4] = fmaxf(e4 * inv * gg1.x + bl1.x, 0.0f);
  out[5] = fmaxf(e5 * inv * gg1.y + bl1.y, 0.0f);
  out[6] = fmaxf(e6 * inv * gg1.z + bl1.z, 0.0f);
  out[7] = fmaxf(e7 * inv * gg1.w + bl1.w, 0.0f);
}

// P4: fused gather1 + LN + ReLU -> LDS y1 -> GEMM2 -> B (h2, fp16).
// 64 rows per block: 4 gather passes of 16 rows, then MFMA from LDS.
__global__ __launch_bounds__(256) void k_mid(
    const uint4* __restrict__ hb, const int4* __restrict__ meta,
    const u32* __restrict__ csr,
    const float* __restrict__ b, const float* __restrict__ g,
    const float* __restrict__ bln,
    const u16* __restrict__ Wt2, u16* __restrict__ outB, int n) {
  __shared__ alignas(16) u16 sY[64 * 136];
  const int tid = threadIdx.x;
  const int sl = tid & 15;
  const int row0 = blockIdx.x * 64;

  for (int p = 0; p < 4; p++) {
    int lr = p * 16 + (tid >> 4);           // 0..63
    int row = row0 + lr;
    float o[8];
    gather_ln_core(hb, meta, csr, b, g, bln, row, n, sl, o);
    uint4 pk;
    pk.x = ((u32)f2h(o[1]) << 16) | (u32)f2h(o[0]);
    pk.y = ((u32)f2h(o[3]) << 16) | (u32)f2h(o[2]);
    pk.z = ((u32)f2h(o[5]) << 16) | (u32)f2h(o[4]);
    pk.w = ((u32)f2h(o[7]) << 16) | (u32)f2h(o[6]);
    *(uint4*)(sY + lr * 136 + sl * 8) = pk;
  }
  __syncthreads();

  // GEMM2 from LDS y1
  const int lane = tid & 63, wv = tid >> 6;
  const int m = lane & 15, q = lane >> 4;
  f32x4 acc[8];
#pragma unroll
  for (int ct = 0; ct < 8; ct++) acc[ct] = (f32x4)(0.0f);
  const u16* ap = sY + (wv * 16 + m) * 136 + q * 8;
#pragma unroll
  for (int kk = 0; kk < 4; kk++) {
    half8 a = *(const half8*)(ap + kk * 32);
#pragma unroll
    for (int ct = 0; ct < 8; ct++) {
      half8 bfr = *(const half8*)(Wt2 + (ct * 16 + m) * D + kk * 32 + q * 8);
      acc[ct] = __builtin_amdgcn_mfma_f32_16x16x32_f16(a, bfr, acc[ct], 0, 0, 0);
    }
  }
#pragma unroll
  for (int ct = 0; ct < 8; ct++) {
#pragma unroll
    for (int rg = 0; rg < 4; rg++) {
      int rr = row0 + wv * 16 + q * 4 + rg;
      if (rr < n) outB[(size_t)rr * D + ct * 16 + m] = f2h(acc[ct][rg]);
    }
  }
}

// P5: gather2 + LN + ReLU + residual -> fp32 out.
__global__ __launch_bounds__(256) void k_gather2(
    const uint4* __restrict__ hb, const int4* __restrict__ meta,
    const u32* __restrict__ csr,
    const float* __restrict__ b, const float* __restrict__ g,
    const float* __restrict__ bln, const float* __restrict__ resid,
    float* __restrict__ outf, int n) {
  const int tid = threadIdx.x;
  const int sl = tid & 15;
  const int row = blockIdx.x * 16 + (tid >> 4);
  float o[8];
  gather_ln_core(hb, meta, csr, b, g, bln, row, n, sl, o);
  if (row >= n) return;
  size_t base = (size_t)row * D + sl * 8;
  float4 r0 = *(const float4*)(resid + base);
  float4 r1 = *(const float4*)(resid + base + 4);
  *(float4*)(outf + base) =
      make_float4(o[0] + r0.x, o[1] + r0.y, o[2] + r0.z, o[3] + r0.w);
  *(float4*)(outf + base + 4) =
      make_float4(o[4] + r1.x, o[5] + r1.y, o[6] + r1.z, o[7] + r1.w);
}

// ---------------------------------------------------------------------------
extern "C" void kernel_launch(void* const* d_in, const int* in_sizes, int n_in,
                              void* d_out, int out_size, void* d_ws, size_t ws_size,
                              hipStream_t stream) {
  const float* x    = (const float*)d_in[0];
  const int*   ei   = (const int*)d_in[1];
  const float* W1   = (const float*)d_in[2];
  const float* b1   = (const float*)d_in[3];
  const float* g1   = (const float*)d_in[4];
  const float* bl1  = (const float*)d_in[5];
  const float* W2   = (const float*)d_in[6];
  const float* b2   = (const float*)d_in[7];
  const float* g2   = (const float*)d_in[8];
  const float* bl2  = (const float*)d_in[9];

  const int N = in_sizes[0] / D;
  const int E = in_sizes[1] / 2;
  const int* src = ei;
  const int* dst = ei + E;

  size_t off = 0;
  auto walloc = [&](size_t bytes) {
    void* p = (char*)d_ws + off;
    off = (off + bytes + 255) & ~(size_t)255;
    return p;
  };
  int*   deg     = (int*)walloc((size_t)N * 4);
  float* dinv    = (float*)walloc((size_t)N * 4);
  int4*  meta    = (int4*)walloc((size_t)N * 16);
  int*   counter = (int*)walloc(256);
  int*   rank    = (int*)walloc((size_t)E * 4);
  u32*   csr     = (u32*)walloc((size_t)E * 4);
  u16*   A       = (u16*)walloc((size_t)N * D * 2);   // h1 (fp16)
  u16*   B       = (u16*)walloc((size_t)N * D * 2);   // h2 (fp16)
  u16*   Wt1     = (u16*)walloc((size_t)D * D * 2);
  u16*   Wt2     = (u16*)walloc((size_t)D * D * 2);
  float* O       = (float*)d_out;

  const int DB = (E + 1023) / 1024;      // deg blocks (4 edges/thread)
  const int FB = (E + 1023) / 1024;      // fill blocks
  const int GB = (N + 63) / 64;          // gemm/mid blocks

  // P0: prep (zero deg/counter + weight converts)
  int p0 = max(N, 2 * D * D);
  k_prep<<<(p0 + 255) / 256, 256, 0, stream>>>(W1, W2, Wt1, Wt2, deg, counter, N);
  // P1: degrees + ranks || GEMM1 (x @ W1 -> A)
  k_deg_gemm1<<<DB + GB, 256, 0, stream>>>(dst, deg, rank, E, DB, x, Wt1, A, N);
  // P2: alloc (dinv + meta)
  k_alloc<<<(N + 255) / 256, 256, 0, stream>>>(deg, dinv, meta, counter, N);
  // P3: CSR fill
  k_fill<<<FB, 256, 0, stream>>>(src, dst, rank, meta, dinv, csr, E);
  // P4: gather1 + LN + ReLU + GEMM2 -> B
  k_mid<<<GB, 256, 0, stream>>>((const uint4*)A, meta, csr, b1, g1, bl1,
                                Wt2, B, N);
  // P5: gather2 + LN + ReLU + residual -> O
  k_gather2<<<(N + 15) / 16, 256, 0, stream>>>((const uint4*)B, meta, csr,
                                               b2, g2, bl2, x, O, N);
}

// Round 9
// 217.891 us; speedup vs baseline: 1.1640x; 1.0319x over previous
//
#include <hip/hip_runtime.h>
#include <hip/hip_fp16.h>

#define D 128
#define EPS 1e-5f
#define KB 64          // coarse count/scatter blocks
#define NBSH 7         // bucket = dst >> 7
#define BUCKW 128      // dsts per bucket

typedef unsigned int u32;
typedef unsigned short u16;
typedef __attribute__((ext_vector_type(8))) _Float16 half8;  // mfma A/B frag
typedef __attribute__((ext_vector_type(4))) float f32x4;

__device__ inline u16 f2h(float x) {
  _Float16 t = (_Float16)x;
  return __builtin_bit_cast(u16, t);
}
__device__ inline __half2 b2h2(u32 u) { return __builtin_bit_cast(__half2, u); }

// ---------------------------------------------------------------------------
// P0: convert W1,W2 fp32[k][c] -> fp16 Wt[c][k]. (Sort pipeline writes every
// cell it reads — no zero-init needed anywhere.)
__global__ __launch_bounds__(256) void k_prep(const float* __restrict__ W1,
                                              const float* __restrict__ W2,
                                              u16* __restrict__ Wt1,
                                              u16* __restrict__ Wt2) {
  int i = blockIdx.x * 256 + threadIdx.x;
  if (i < 2 * D * D) {
    const float* W = (i < D * D) ? W1 : W2;
    u16* Wt = (i < D * D) ? Wt1 : Wt2;
    int ii = i & (D * D - 1);
    int k = ii >> 7, c = ii & 127;
    Wt[c * D + k] = f2h(W[ii]);
  }
}

// ---------------------------------------------------------------------------
// LDS-free MFMA GEMM body (global A). A-frag: lane(m,q)=A[r0+m][k=q*8+j];
// B from Wt[c][k] (L2-hot); D: col=ct*16+m, row=q*4+reg.
template <bool F32IN>
__device__ __forceinline__ void gemm_body(const void* __restrict__ in_,
                                          const u16* __restrict__ Wt,
                                          u16* __restrict__ out, int nrows,
                                          int blk) {
  const int tid = threadIdx.x;
  const int lane = tid & 63, wv = tid >> 6;
  const int m = lane & 15, q = lane >> 4;
  const int r0 = blk * 64 + wv * 16;
  const int rowa = min(r0 + m, nrows - 1);

  f32x4 acc[8];
#pragma unroll
  for (int ct = 0; ct < 8; ct++) acc[ct] = (f32x4)(0.0f);

#pragma unroll
  for (int kk = 0; kk < 4; kk++) {
    const int kbase = kk * 32 + q * 8;
    half8 a;
    if (F32IN) {
      const float* in = (const float*)in_;
      float4 v0 = *(const float4*)(in + (size_t)rowa * D + kbase);
      float4 v1 = *(const float4*)(in + (size_t)rowa * D + kbase + 4);
      a[0] = (_Float16)v0.x; a[1] = (_Float16)v0.y;
      a[2] = (_Float16)v0.z; a[3] = (_Float16)v0.w;
      a[4] = (_Float16)v1.x; a[5] = (_Float16)v1.y;
      a[6] = (_Float16)v1.z; a[7] = (_Float16)v1.w;
    } else {
      const u16* in = (const u16*)in_;
      a = *(const half8*)(in + (size_t)rowa * D + kbase);
    }
#pragma unroll
    for (int ct = 0; ct < 8; ct++) {
      half8 b = *(const half8*)(Wt + (ct * 16 + m) * D + kbase);
      acc[ct] = __builtin_amdgcn_mfma_f32_16x16x32_f16(a, b, acc[ct], 0, 0, 0);
    }
  }

#pragma unroll
  for (int ct = 0; ct < 8; ct++) {
#pragma unroll
    for (int rg = 0; rg < 4; rg++) {
      int rr = r0 + q * 4 + rg;
      if (rr < nrows) out[(size_t)rr * D + ct * 16 + m] = f2h(acc[ct][rg]);
    }
  }
}

// ph1: coarse-bucket count, 8-deep batched (blocks [0,KB)) || GEMM1.
__global__ __launch_bounds__(256) void k_count_gemm1(
    const int* __restrict__ dst, int* __restrict__ cnt, int E, int NB, int EPB,
    const float* __restrict__ x, const u16* __restrict__ Wt1,
    u16* __restrict__ A, int nrows) {
  if (blockIdx.x < (u32)KB) {
    __shared__ int hist[512];
    const int k = blockIdx.x, tid = threadIdx.x;
    for (int i = tid; i < NB; i += 256) hist[i] = 0;
    __syncthreads();
    const int e0 = k * EPB, e1 = min(E, e0 + EPB);
    for (int base = e0 + tid; base < e1; base += 2048) {
      int dd[8];
#pragma unroll
      for (int i = 0; i < 8; i++) {
        int e = base + i * 256;
        dd[i] = (e < e1) ? dst[e] : -1;
      }
#pragma unroll
      for (int i = 0; i < 8; i++)
        if (dd[i] >= 0) atomicAdd(&hist[dd[i] >> NBSH], 1);
    }
    __syncthreads();
    for (int b = tid; b < NB; b += 256) cnt[b * KB + k] = hist[b];
  } else {
    gemm_body<true>(x, Wt1, A, nrows, blockIdx.x - KB);
  }
}

// ph2: single-block exclusive scan of cnt[M] (bucket-major, M=NB*KB),
// prefetch-pipelined. Emits bsv[b] = bucket start, bsv[NB] = E.
__global__ __launch_bounds__(1024) void k_scan(int* __restrict__ cnt, int M,
                                               int NB, int* __restrict__ bsv,
                                               int E) {
  __shared__ int wt[16];
  const int tid = threadIdx.x;
  const int lane = tid & 63, wid = tid >> 6;
  const int chunks = (M + 1023) >> 10;
  int running = 0;
  int i = tid;
  int v = (i < M) ? cnt[i] : 0;
  for (int c = 0; c < chunks; c++) {
    int inext = i + 1024;
    int vnext = (c + 1 < chunks && inext < M) ? cnt[inext] : 0;  // in flight
    int incl = v;
#pragma unroll
    for (int o = 1; o < 64; o <<= 1) {
      int t = __shfl_up(incl, o, 64);
      if (lane >= o) incl += t;
    }
    if (lane == 63) wt[wid] = incl;
    __syncthreads();
    int woff = 0, total = 0;
#pragma unroll
    for (int j = 0; j < 16; j++) {
      int t = wt[j];
      if (j < wid) woff += t;
      total += t;
    }
    int excl = running + woff + incl - v;
    if (i < M) {
      cnt[i] = excl;
      if ((i & (KB - 1)) == 0) bsv[i / KB] = excl;
    }
    running += total;
    __syncthreads();
    i = inext;
    v = vnext;
  }
  if (tid == 0) bsv[NB] = E;
}

// ph3: scatter edges into bucket-grouped tmp via LDS cursors, 8-deep batched.
// tmp entry = src:16 | dstlow:7.
__global__ __launch_bounds__(256) void k_scatter(
    const int* __restrict__ src, const int* __restrict__ dst,
    const int* __restrict__ cnt, u32* __restrict__ tmp, int E, int NB,
    int EPB) {
  __shared__ int off[512];
  const int k = blockIdx.x, tid = threadIdx.x;
  for (int b = tid; b < NB; b += 256) off[b] = cnt[b * KB + k];
  __syncthreads();
  const int e0 = k * EPB, e1 = min(E, e0 + EPB);
  for (int base = e0 + tid; base < e1; base += 2048) {
    int dd[8], ss[8];
#pragma unroll
    for (int i = 0; i < 8; i++) {
      int e = base + i * 256;
      dd[i] = (e < e1) ? dst[e] : -1;
      ss[i] = (e < e1) ? src[e] : 0;
    }
#pragma unroll
    for (int i = 0; i < 8; i++) {
      if (dd[i] >= 0) {
        int p = atomicAdd(&off[dd[i] >> NBSH], 1);
        tmp[p] = (u32)ss[i] | ((u32)(dd[i] & (BUCKW - 1)) << 16);
      }
    }
  }
}

// ph4: one block per bucket: fine 128-bin LDS hist + scan -> deg/dinv/meta,
// then dst-sorted csr (entry = src, weights packed in ph5).
__global__ __launch_bounds__(256) void k_bucket(
    const u32* __restrict__ tmp, const int* __restrict__ bsv,
    int4* __restrict__ meta, float* __restrict__ dinv,
    u32* __restrict__ csr, int N) {
  __shared__ int hist[BUCKW];
  __shared__ int sc[BUCKW];
  __shared__ int cur[BUCKW];
  const int b = blockIdx.x, tid = threadIdx.x;
  const int s0 = bsv[b], s1 = bsv[b + 1];
  if (tid < BUCKW) hist[tid] = 0;
  __syncthreads();
  for (int base = s0 + tid; base < s1; base += 1024) {
    int tt[4];
#pragma unroll
    for (int i = 0; i < 4; i++) {
      int idx = base + i * 256;
      tt[i] = (idx < s1) ? (int)tmp[idx] : -1;
    }
#pragma unroll
    for (int i = 0; i < 4; i++)
      if (tt[i] >= 0) atomicAdd(&hist[(tt[i] >> 16) & (BUCKW - 1)], 1);
  }
  __syncthreads();
  if (tid < BUCKW) sc[tid] = hist[tid];
  __syncthreads();
#pragma unroll
  for (int o = 1; o < BUCKW; o <<= 1) {
    int t = 0;
    if (tid < BUCKW && tid >= o) t = sc[tid - o];
    __syncthreads();
    if (tid < BUCKW) sc[tid] += t;
    __syncthreads();
  }
  if (tid < BUCKW) {
    int dg = hist[tid];
    int excl = sc[tid] - dg;
    cur[tid] = excl;
    int d = (b << NBSH) + tid;
    if (d < N) {
      float dv = rsqrtf((float)dg + 1.0f);
      meta[d] = make_int4(s0 + excl, dg, __builtin_bit_cast(int, dv), 0);
      dinv[d] = dv;
    }
  }
  __syncthreads();
  for (int base = s0 + tid; base < s1; base += 1024) {
    int tt[4];
#pragma unroll
    for (int i = 0; i < 4; i++) {
      int idx = base + i * 256;
      tt[i] = (idx < s1) ? (int)tmp[idx] : -1;
    }
#pragma unroll
    for (int i = 0; i < 4; i++) {
      if (tt[i] >= 0) {
        int r = atomicAdd(&cur[(tt[i] >> 16) & (BUCKW - 1)], 1);
        csr[s0 + r] = (u32)tt[i] & 0xffffu;   // src only
      }
    }
  }
}

// ph5: pack weights: csr entry src -> src | fp16(dinv[s]*dinv[d])<<16.
// 4 threads per row for parallelism over the deg loop.
__global__ __launch_bounds__(256) void k_weights(
    const int4* __restrict__ meta, const float* __restrict__ dinv,
    u32* __restrict__ csr, int N) {
  int gid = blockIdx.x * 256 + threadIdx.x;
  int r = gid >> 2, j0 = gid & 3;
  if (r >= N) return;
  int4 mt = meta[r];
  float dv = __builtin_bit_cast(float, mt.z);
  for (int j = j0; j < mt.y; j += 4) {
    u32 s = csr[mt.x + j];
    float w = dinv[s] * dv;
    csr[mt.x + j] = s | ((u32)f2h(w) << 16);
  }
}

// ---------------------------------------------------------------------------
// Gather+LN core (unchanged from R8): row owned by 16 lanes, uint4/lane.
__device__ __forceinline__ void gather_ln_core(
    const uint4* __restrict__ hb, const int4* __restrict__ meta,
    const u32* __restrict__ csr, const float* __restrict__ b,
    const float* __restrict__ g, const float* __restrict__ bln,
    int row, int n, int sl, float out[8]) {
  const bool valid = row < n;
  const int rc = valid ? row : 0;
  int4 mt = meta[rc];
  int beg = mt.x;
  int cnt = valid ? mt.y : 0;
  float dv = __builtin_bit_cast(float, mt.z);
  __half2 sn2 = __float2half2_rn(dv * dv);

  uint4 su = hb[(size_t)rc * 16 + sl];
  __half2 acc0 = __hmul2(b2h2(su.x), sn2);
  __half2 acc1 = __hmul2(b2h2(su.y), sn2);
  __half2 acc2 = __hmul2(b2h2(su.z), sn2);
  __half2 acc3 = __hmul2(b2h2(su.w), sn2);

  int cm = max(cnt, __shfl_xor(cnt, 16, 64));
  cm = max(cm, __shfl_xor(cm, 32, 64));

  for (int j0 = 0; j0 < cm; j0 += 16) {
    u32 e = 0u;
    if (sl < cnt - j0) e = csr[beg + j0 + sl];
    int mm = min(cm - j0, 16);
    for (int j = 0; j < mm; j += 4) {
      u32 e0 = __shfl(e, j, 16),     e1 = __shfl(e, j + 1, 16);
      u32 e2 = __shfl(e, j + 2, 16), e3 = __shfl(e, j + 3, 16);
      uint4 v0 = hb[(size_t)(e0 & 0xffffu) * 16 + sl];
      uint4 v1 = hb[(size_t)(e1 & 0xffffu) * 16 + sl];
      uint4 v2 = hb[(size_t)(e2 & 0xffffu) * 16 + sl];
      uint4 v3 = hb[(size_t)(e3 & 0xffffu) * 16 + sl];
      __half2 w0 = b2h2((e0 >> 16) | (e0 & 0xffff0000u));
      __half2 w1 = b2h2((e1 >> 16) | (e1 & 0xffff0000u));
      __half2 w2 = b2h2((e2 >> 16) | (e2 & 0xffff0000u));
      __half2 w3 = b2h2((e3 >> 16) | (e3 & 0xffff0000u));
      acc0 = __hfma2(b2h2(v0.x), w0, acc0);
      acc1 = __hfma2(b2h2(v0.y), w0, acc1);
      acc2 = __hfma2(b2h2(v0.z), w0, acc2);
      acc3 = __hfma2(b2h2(v0.w), w0, acc3);
      acc0 = __hfma2(b2h2(v1.x), w1, acc0);
      acc1 = __hfma2(b2h2(v1.y), w1, acc1);
      acc2 = __hfma2(b2h2(v1.z), w1, acc2);
      acc3 = __hfma2(b2h2(v1.w), w1, acc3);
      acc0 = __hfma2(b2h2(v2.x), w2, acc0);
      acc1 = __hfma2(b2h2(v2.y), w2, acc1);
      acc2 = __hfma2(b2h2(v2.z), w2, acc2);
      acc3 = __hfma2(b2h2(v2.w), w2, acc3);
      acc0 = __hfma2(b2h2(v3.x), w3, acc0);
      acc1 = __hfma2(b2h2(v3.y), w3, acc1);
      acc2 = __hfma2(b2h2(v3.z), w3, acc2);
      acc3 = __hfma2(b2h2(v3.w), w3, acc3);
    }
  }

  float2 f0 = __half22float2(acc0);
  float2 f1 = __half22float2(acc1);
  float2 f2 = __half22float2(acc2);
  float2 f3 = __half22float2(acc3);
  int d0 = sl * 8;
  float4 bb0 = *(const float4*)(b + d0);
  float4 bb1 = *(const float4*)(b + d0 + 4);
  float a0 = f0.x + bb0.x, a1 = f0.y + bb0.y;
  float a2 = f1.x + bb0.z, a3 = f1.y + bb0.w;
  float a4 = f2.x + bb1.x, a5 = f2.y + bb1.y;
  float a6 = f3.x + bb1.z, a7 = f3.y + bb1.w;

  float sum = ((a0 + a1) + (a2 + a3)) + ((a4 + a5) + (a6 + a7));
#pragma unroll
  for (int o = 8; o >= 1; o >>= 1) sum += __shfl_xor(sum, o, 16);
  float mu = sum * (1.0f / 128.0f);
  float e0 = a0 - mu, e1 = a1 - mu, e2 = a2 - mu, e3 = a3 - mu;
  float e4 = a4 - mu, e5 = a5 - mu, e6 = a6 - mu, e7 = a7 - mu;
  float vs = ((e0 * e0 + e1 * e1) + (e2 * e2 + e3 * e3)) +
             ((e4 * e4 + e5 * e5) + (e6 * e6 + e7 * e7));
#pragma unroll
  for (int o = 8; o >= 1; o >>= 1) vs += __shfl_xor(vs, o, 16);
  float inv = rsqrtf(vs * (1.0f / 128.0f) + EPS);

  float4 gg0 = *(const float4*)(g + d0);
  float4 gg1 = *(const float4*)(g + d0 + 4);
  float4 bl0 = *(const float4*)(bln + d0);
  float4 bl1 = *(const float4*)(bln + d0 + 4);
  out[0] = fmaxf(e0 * inv * gg0.x + bl0.x, 0.0f);
  out[1] = fmaxf(e1 * inv * gg0.y + bl0.y, 0.0f);
  out[2] = fmaxf(e2 * inv * gg0.z + bl0.z, 0.0f);
  out[3] = fmaxf(e3 * inv * gg0.w + bl0.w, 0.0f);
  out[4] = fmaxf(e4 * inv * gg1.x + bl1.x, 0.0f);
  out[5] = fmaxf(e5 * inv * gg1.y + bl1.y, 0.0f);
  out[6] = fmaxf(e6 * inv * gg1.z + bl1.z, 0.0f);
  out[7] = fmaxf(e7 * inv * gg1.w + bl1.w, 0.0f);
}

// P6: fused gather1 + LN + ReLU -> LDS y1 -> GEMM2 -> B (h2, fp16).
__global__ __launch_bounds__(256) void k_mid(
    const uint4* __restrict__ hb, const int4* __restrict__ meta,
    const u32* __restrict__ csr,
    const float* __restrict__ b, const float* __restrict__ g,
    const float* __restrict__ bln,
    const u16* __restrict__ Wt2, u16* __restrict__ outB, int n) {
  __shared__ alignas(16) u16 sY[64 * 136];
  const int tid = threadIdx.x;
  const int sl = tid & 15;
  const int row0 = blockIdx.x * 64;

  for (int p = 0; p < 4; p++) {
    int lr = p * 16 + (tid >> 4);
    int row = row0 + lr;
    float o[8];
    gather_ln_core(hb, meta, csr, b, g, bln, row, n, sl, o);
    uint4 pk;
    pk.x = ((u32)f2h(o[1]) << 16) | (u32)f2h(o[0]);
    pk.y = ((u32)f2h(o[3]) << 16) | (u32)f2h(o[2]);
    pk.z = ((u32)f2h(o[5]) << 16) | (u32)f2h(o[4]);
    pk.w = ((u32)f2h(o[7]) << 16) | (u32)f2h(o[6]);
    *(uint4*)(sY + lr * 136 + sl * 8) = pk;
  }
  __syncthreads();

  const int lane = tid & 63, wv = tid >> 6;
  const int m = lane & 15, q = lane >> 4;
  f32x4 acc[8];
#pragma unroll
  for (int ct = 0; ct < 8; ct++) acc[ct] = (f32x4)(0.0f);
  const u16* ap = sY + (wv * 16 + m) * 136 + q * 8;
#pragma unroll
  for (int kk = 0; kk < 4; kk++) {
    half8 a = *(const half8*)(ap + kk * 32);
#pragma unroll
    for (int ct = 0; ct < 8; ct++) {
      half8 bfr = *(const half8*)(Wt2 + (ct * 16 + m) * D + kk * 32 + q * 8);
      acc[ct] = __builtin_amdgcn_mfma_f32_16x16x32_f16(a, bfr, acc[ct], 0, 0, 0);
    }
  }
#pragma unroll
  for (int ct = 0; ct < 8; ct++) {
#pragma unroll
    for (int rg = 0; rg < 4; rg++) {
      int rr = row0 + wv * 16 + q * 4 + rg;
      if (rr < n) outB[(size_t)rr * D + ct * 16 + m] = f2h(acc[ct][rg]);
    }
  }
}

// P7: gather2 + LN + ReLU + residual -> fp32 out.
__global__ __launch_bounds__(256) void k_gather2(
    const uint4* __restrict__ hb, const int4* __restrict__ meta,
    const u32* __restrict__ csr,
    const float* __restrict__ b, const float* __restrict__ g,
    const float* __restrict__ bln, const float* __restrict__ resid,
    float* __restrict__ outf, int n) {
  const int tid = threadIdx.x;
  const int sl = tid & 15;
  const int row = blockIdx.x * 16 + (tid >> 4);
  float o[8];
  gather_ln_core(hb, meta, csr, b, g, bln, row, n, sl, o);
  if (row >= n) return;
  size_t base = (size_t)row * D + sl * 8;
  float4 r0 = *(const float4*)(resid + base);
  float4 r1 = *(const float4*)(resid + base + 4);
  *(float4*)(outf + base) =
      make_float4(o[0] + r0.x, o[1] + r0.y, o[2] + r0.z, o[3] + r0.w);
  *(float4*)(outf + base + 4) =
      make_float4(o[4] + r1.x, o[5] + r1.y, o[6] + r1.z, o[7] + r1.w);
}

// ---------------------------------------------------------------------------
extern "C" void kernel_launch(void* const* d_in, const int* in_sizes, int n_in,
                              void* d_out, int out_size, void* d_ws, size_t ws_size,
                              hipStream_t stream) {
  const float* x    = (const float*)d_in[0];
  const int*   ei   = (const int*)d_in[1];
  const float* W1   = (const float*)d_in[2];
  const float* b1   = (const float*)d_in[3];
  const float* g1   = (const float*)d_in[4];
  const float* bl1  = (const float*)d_in[5];
  const float* W2   = (const float*)d_in[6];
  const float* b2   = (const float*)d_in[7];
  const float* g2   = (const float*)d_in[8];
  const float* bl2  = (const float*)d_in[9];

  const int N = in_sizes[0] / D;
  const int E = in_sizes[1] / 2;
  const int* src = ei;
  const int* dst = ei + E;

  const int NB  = (N + BUCKW - 1) / BUCKW;  // 391 coarse buckets
  const int M   = NB * KB;
  const int EPB = (E + KB - 1) / KB;        // edges per count/scatter block
  const int GB  = (N + 63) / 64;            // gemm/mid blocks

  size_t off = 0;
  auto walloc = [&](size_t bytes) {
    void* p = (char*)d_ws + off;
    off = (off + bytes + 255) & ~(size_t)255;
    return p;
  };
  int*   cnt   = (int*)walloc((size_t)M * 4);
  int*   bsv   = (int*)walloc((size_t)(NB + 1) * 4);
  u32*   tmp   = (u32*)walloc((size_t)E * 4);
  u32*   csr   = (u32*)walloc((size_t)E * 4);
  int4*  meta  = (int4*)walloc((size_t)N * 16);
  float* dinv  = (float*)walloc((size_t)N * 4);
  u16*   A     = (u16*)walloc((size_t)N * D * 2);   // h1 (fp16)
  u16*   B     = (u16*)walloc((size_t)N * D * 2);   // h2 (fp16)
  u16*   Wt1   = (u16*)walloc((size_t)D * D * 2);
  u16*   Wt2   = (u16*)walloc((size_t)D * D * 2);
  float* O     = (float*)d_out;

  // P0: weight converts
  k_prep<<<(2 * D * D + 255) / 256, 256, 0, stream>>>(W1, W2, Wt1, Wt2);
  // ph1: coarse count || GEMM1 (x @ W1 -> A)
  k_count_gemm1<<<KB + GB, 256, 0, stream>>>(dst, cnt, E, NB, EPB, x, Wt1, A, N);
  // ph2: scan
  k_scan<<<1, 1024, 0, stream>>>(cnt, M, NB, bsv, E);
  // ph3: scatter into buckets
  k_scatter<<<KB, 256, 0, stream>>>(src, dst, cnt, tmp, E, NB, EPB);
  // ph4: per-bucket fine sort -> csr + meta + dinv
  k_bucket<<<NB, 256, 0, stream>>>(tmp, bsv, meta, dinv, csr, N);
  // ph5: pack weights
  k_weights<<<(N * 4 + 255) / 256, 256, 0, stream>>>(meta, dinv, csr, N);
  // P6: gather1 + LN + ReLU + GEMM2 -> B
  k_mid<<<GB, 256, 0, stream>>>((const uint4*)A, meta, csr, b1, g1, bl1,
                                Wt2, B, N);
  // P7: gather2 + LN + ReLU + residual -> O
  k_gather2<<<(N + 15) / 16, 256, 0, stream>>>((const uint4*)B, meta, csr,
                                               b2, g2, bl2, x, O, N);
}

// Round 10
// 214.870 us; speedup vs baseline: 1.1804x; 1.0141x over previous
//
#include <hip/hip_runtime.h>
#include <hip/hip_fp16.h>

#define D 128
#define EPS 1e-5f
#define KB 64          // coarse count/scatter blocks
#define NBSH 7         // bucket = dst >> 7
#define BUCKW 128      // dsts per bucket

typedef unsigned int u32;
typedef unsigned short u16;
typedef unsigned char u8;
typedef __attribute__((ext_vector_type(8))) _Float16 half8;  // mfma A/B frag
typedef __attribute__((ext_vector_type(4))) float f32x4;
typedef __attribute__((ext_vector_type(2))) float f32x2;

__device__ inline u16 f2h(float x) {
  _Float16 t = (_Float16)x;
  return __builtin_bit_cast(u16, t);
}
__device__ inline u8 f2fp8(float x) {
  return (u8)(__builtin_amdgcn_cvt_pk_fp8_f32(x, x, 0, false) & 0xff);
}

// ---------------------------------------------------------------------------
// P0: convert W1,W2 fp32[k][c] -> fp16 Wt[c][k].
__global__ __launch_bounds__(256) void k_prep(const float* __restrict__ W1,
                                              const float* __restrict__ W2,
                                              u16* __restrict__ Wt1,
                                              u16* __restrict__ Wt2) {
  int i = blockIdx.x * 256 + threadIdx.x;
  if (i < 2 * D * D) {
    const float* W = (i < D * D) ? W1 : W2;
    u16* Wt = (i < D * D) ? Wt1 : Wt2;
    int ii = i & (D * D - 1);
    int k = ii >> 7, c = ii & 127;
    Wt[c * D + k] = f2h(W[ii]);
  }
}

// ---------------------------------------------------------------------------
// LDS-free MFMA GEMM body; OUTPUT IS FP8 (e4m3). A-frag from global
// (contiguous 16B in k); B from Wt[c][k] (L2-hot); D: col=ct*16+m, row=q*4+reg.
template <bool F32IN>
__device__ __forceinline__ void gemm_body(const void* __restrict__ in_,
                                          const u16* __restrict__ Wt,
                                          u8* __restrict__ out, int nrows,
                                          int blk) {
  const int tid = threadIdx.x;
  const int lane = tid & 63, wv = tid >> 6;
  const int m = lane & 15, q = lane >> 4;
  const int r0 = blk * 64 + wv * 16;
  const int rowa = min(r0 + m, nrows - 1);

  f32x4 acc[8];
#pragma unroll
  for (int ct = 0; ct < 8; ct++) acc[ct] = (f32x4)(0.0f);

#pragma unroll
  for (int kk = 0; kk < 4; kk++) {
    const int kbase = kk * 32 + q * 8;
    half8 a;
    if (F32IN) {
      const float* in = (const float*)in_;
      float4 v0 = *(const float4*)(in + (size_t)rowa * D + kbase);
      float4 v1 = *(const float4*)(in + (size_t)rowa * D + kbase + 4);
      a[0] = (_Float16)v0.x; a[1] = (_Float16)v0.y;
      a[2] = (_Float16)v0.z; a[3] = (_Float16)v0.w;
      a[4] = (_Float16)v1.x; a[5] = (_Float16)v1.y;
      a[6] = (_Float16)v1.z; a[7] = (_Float16)v1.w;
    } else {
      const u16* in = (const u16*)in_;
      a = *(const half8*)(in + (size_t)rowa * D + kbase);
    }
#pragma unroll
    for (int ct = 0; ct < 8; ct++) {
      half8 b = *(const half8*)(Wt + (ct * 16 + m) * D + kbase);
      acc[ct] = __builtin_amdgcn_mfma_f32_16x16x32_f16(a, b, acc[ct], 0, 0, 0);
    }
  }

#pragma unroll
  for (int ct = 0; ct < 8; ct++) {
#pragma unroll
    for (int rg = 0; rg < 4; rg++) {
      int rr = r0 + q * 4 + rg;
      if (rr < nrows) out[(size_t)rr * D + ct * 16 + m] = f2fp8(acc[ct][rg]);
    }
  }
}

// ph1: coarse-bucket count, 8-deep batched (blocks [0,KB)) || GEMM1.
__global__ __launch_bounds__(256) void k_count_gemm1(
    const int* __restrict__ dst, int* __restrict__ cnt, int E, int NB, int EPB,
    const float* __restrict__ x, const u16* __restrict__ Wt1,
    u8* __restrict__ A, int nrows) {
  if (blockIdx.x < (u32)KB) {
    __shared__ int hist[512];
    const int k = blockIdx.x, tid = threadIdx.x;
    for (int i = tid; i < NB; i += 256) hist[i] = 0;
    __syncthreads();
    const int e0 = k * EPB, e1 = min(E, e0 + EPB);
    for (int base = e0 + tid; base < e1; base += 2048) {
      int dd[8];
#pragma unroll
      for (int i = 0; i < 8; i++) {
        int e = base + i * 256;
        dd[i] = (e < e1) ? dst[e] : -1;
      }
#pragma unroll
      for (int i = 0; i < 8; i++)
        if (dd[i] >= 0) atomicAdd(&hist[dd[i] >> NBSH], 1);
    }
    __syncthreads();
    for (int b = tid; b < NB; b += 256) cnt[b * KB + k] = hist[b];
  } else {
    gemm_body<true>(x, Wt1, A, nrows, blockIdx.x - KB);
  }
}

// ph2: single-block exclusive scan of cnt[M] (bucket-major), prefetch-piped.
__global__ __launch_bounds__(1024) void k_scan(int* __restrict__ cnt, int M,
                                               int NB, int* __restrict__ bsv,
                                               int E) {
  __shared__ int wt[16];
  const int tid = threadIdx.x;
  const int lane = tid & 63, wid = tid >> 6;
  const int chunks = (M + 1023) >> 10;
  int running = 0;
  int i = tid;
  int v = (i < M) ? cnt[i] : 0;
  for (int c = 0; c < chunks; c++) {
    int inext = i + 1024;
    int vnext = (c + 1 < chunks && inext < M) ? cnt[inext] : 0;
    int incl = v;
#pragma unroll
    for (int o = 1; o < 64; o <<= 1) {
      int t = __shfl_up(incl, o, 64);
      if (lane >= o) incl += t;
    }
    if (lane == 63) wt[wid] = incl;
    __syncthreads();
    int woff = 0, total = 0;
#pragma unroll
    for (int j = 0; j < 16; j++) {
      int t = wt[j];
      if (j < wid) woff += t;
      total += t;
    }
    int excl = running + woff + incl - v;
    if (i < M) {
      cnt[i] = excl;
      if ((i & (KB - 1)) == 0) bsv[i / KB] = excl;
    }
    running += total;
    __syncthreads();
    i = inext;
    v = vnext;
  }
  if (tid == 0) bsv[NB] = E;
}

// ph3: scatter edges into bucket-grouped tmp via LDS cursors, 8-deep batched.
__global__ __launch_bounds__(256) void k_scatter(
    const int* __restrict__ src, const int* __restrict__ dst,
    const int* __restrict__ cnt, u32* __restrict__ tmp, int E, int NB,
    int EPB) {
  __shared__ int off[512];
  const int k = blockIdx.x, tid = threadIdx.x;
  for (int b = tid; b < NB; b += 256) off[b] = cnt[b * KB + k];
  __syncthreads();
  const int e0 = k * EPB, e1 = min(E, e0 + EPB);
  for (int base = e0 + tid; base < e1; base += 2048) {
    int dd[8], ss[8];
#pragma unroll
    for (int i = 0; i < 8; i++) {
      int e = base + i * 256;
      dd[i] = (e < e1) ? dst[e] : -1;
      ss[i] = (e < e1) ? src[e] : 0;
    }
#pragma unroll
    for (int i = 0; i < 8; i++) {
      if (dd[i] >= 0) {
        int p = atomicAdd(&off[dd[i] >> NBSH], 1);
        tmp[p] = (u32)ss[i] | ((u32)(dd[i] & (BUCKW - 1)) << 16);
      }
    }
  }
}

// ph4: one block per bucket: fine 128-bin LDS hist + scan -> deg/dinv/meta,
// then dst-sorted csr (entry = src).
__global__ __launch_bounds__(256) void k_bucket(
    const u32* __restrict__ tmp, const int* __restrict__ bsv,
    int4* __restrict__ meta, float* __restrict__ dinv,
    u32* __restrict__ csr, int N) {
  __shared__ int hist[BUCKW];
  __shared__ int sc[BUCKW];
  __shared__ int cur[BUCKW];
  const int b = blockIdx.x, tid = threadIdx.x;
  const int s0 = bsv[b], s1 = bsv[b + 1];
  if (tid < BUCKW) hist[tid] = 0;
  __syncthreads();
  for (int base = s0 + tid; base < s1; base += 1024) {
    int tt[4];
#pragma unroll
    for (int i = 0; i < 4; i++) {
      int idx = base + i * 256;
      tt[i] = (idx < s1) ? (int)tmp[idx] : -1;
    }
#pragma unroll
    for (int i = 0; i < 4; i++)
      if (tt[i] >= 0) atomicAdd(&hist[(tt[i] >> 16) & (BUCKW - 1)], 1);
  }
  __syncthreads();
  if (tid < BUCKW) sc[tid] = hist[tid];
  __syncthreads();
#pragma unroll
  for (int o = 1; o < BUCKW; o <<= 1) {
    int t = 0;
    if (tid < BUCKW && tid >= o) t = sc[tid - o];
    __syncthreads();
    if (tid < BUCKW) sc[tid] += t;
    __syncthreads();
  }
  if (tid < BUCKW) {
    int dg = hist[tid];
    int excl = sc[tid] - dg;
    cur[tid] = excl;
    int d = (b << NBSH) + tid;
    if (d < N) {
      float dv = rsqrtf((float)dg + 1.0f);
      meta[d] = make_int4(s0 + excl, dg, __builtin_bit_cast(int, dv), 0);
      dinv[d] = dv;
    }
  }
  __syncthreads();
  for (int base = s0 + tid; base < s1; base += 1024) {
    int tt[4];
#pragma unroll
    for (int i = 0; i < 4; i++) {
      int idx = base + i * 256;
      tt[i] = (idx < s1) ? (int)tmp[idx] : -1;
    }
#pragma unroll
    for (int i = 0; i < 4; i++) {
      if (tt[i] >= 0) {
        int r = atomicAdd(&cur[(tt[i] >> 16) & (BUCKW - 1)], 1);
        csr[s0 + r] = (u32)tt[i] & 0xffffu;
      }
    }
  }
}

// ph5: pack weights: csr entry src -> src | fp16(dinv[s]*dinv[d])<<16.
__global__ __launch_bounds__(256) void k_weights(
    const int4* __restrict__ meta, const float* __restrict__ dinv,
    u32* __restrict__ csr, int N) {
  int gid = blockIdx.x * 256 + threadIdx.x;
  int r = gid >> 2, j0 = gid & 3;
  if (r >= N) return;
  int4 mt = meta[r];
  float dv = __builtin_bit_cast(float, mt.z);
  for (int j = j0; j < mt.y; j += 4) {
    u32 s = csr[mt.x + j];
    float w = dinv[s] * dv;
    csr[mt.x + j] = s | ((u32)f2h(w) << 16);
  }
}

// ---------------------------------------------------------------------------
// Gather+LN core — FP8 h rows (128 B), fp32 accumulation.
// Row owned by 16 lanes, uint2 (8 fp8) per lane.
__device__ __forceinline__ void gather_ln_core(
    const uint2* __restrict__ hb, const int4* __restrict__ meta,
    const u32* __restrict__ csr, const float* __restrict__ b,
    const float* __restrict__ g, const float* __restrict__ bln,
    int row, int n, int sl, float out[8]) {
  const bool valid = row < n;
  const int rc = valid ? row : 0;
  int4 mt = meta[rc];
  int beg = mt.x;
  int cnt = valid ? mt.y : 0;
  float dv = __builtin_bit_cast(float, mt.z);
  float sn = dv * dv;

  float acc[8];
  {
    uint2 su = hb[(size_t)rc * 16 + sl];
    f32x2 p0 = __builtin_amdgcn_cvt_pk_f32_fp8(su.x, false);
    f32x2 p1 = __builtin_amdgcn_cvt_pk_f32_fp8(su.x, true);
    f32x2 p2 = __builtin_amdgcn_cvt_pk_f32_fp8(su.y, false);
    f32x2 p3 = __builtin_amdgcn_cvt_pk_f32_fp8(su.y, true);
    acc[0] = p0[0] * sn; acc[1] = p0[1] * sn;
    acc[2] = p1[0] * sn; acc[3] = p1[1] * sn;
    acc[4] = p2[0] * sn; acc[5] = p2[1] * sn;
    acc[6] = p3[0] * sn; acc[7] = p3[1] * sn;
  }

  int cm = max(cnt, __shfl_xor(cnt, 16, 64));
  cm = max(cm, __shfl_xor(cm, 32, 64));

  for (int j0 = 0; j0 < cm; j0 += 16) {
    u32 e = 0u;
    if (sl < cnt - j0) e = csr[beg + j0 + sl];   // lanes past cnt: e=0 => w=0
    int mm = min(cm - j0, 16);
    for (int j = 0; j < mm; j += 4) {
      u32 e0 = __shfl(e, j, 16),     e1 = __shfl(e, j + 1, 16);
      u32 e2 = __shfl(e, j + 2, 16), e3 = __shfl(e, j + 3, 16);
      uint2 v0 = hb[(size_t)(e0 & 0xffffu) * 16 + sl];
      uint2 v1 = hb[(size_t)(e1 & 0xffffu) * 16 + sl];
      uint2 v2 = hb[(size_t)(e2 & 0xffffu) * 16 + sl];
      uint2 v3 = hb[(size_t)(e3 & 0xffffu) * 16 + sl];
      float w0 = (float)__builtin_bit_cast(_Float16, (u16)(e0 >> 16));
      float w1 = (float)__builtin_bit_cast(_Float16, (u16)(e1 >> 16));
      float w2 = (float)__builtin_bit_cast(_Float16, (u16)(e2 >> 16));
      float w3 = (float)__builtin_bit_cast(_Float16, (u16)(e3 >> 16));
      f32x2 p;
      p = __builtin_amdgcn_cvt_pk_f32_fp8(v0.x, false);
      acc[0] = fmaf(p[0], w0, acc[0]); acc[1] = fmaf(p[1], w0, acc[1]);
      p = __builtin_amdgcn_cvt_pk_f32_fp8(v0.x, true);
      acc[2] = fmaf(p[0], w0, acc[2]); acc[3] = fmaf(p[1], w0, acc[3]);
      p = __builtin_amdgcn_cvt_pk_f32_fp8(v0.y, false);
      acc[4] = fmaf(p[0], w0, acc[4]); acc[5] = fmaf(p[1], w0, acc[5]);
      p = __builtin_amdgcn_cvt_pk_f32_fp8(v0.y, true);
      acc[6] = fmaf(p[0], w0, acc[6]); acc[7] = fmaf(p[1], w0, acc[7]);

      p = __builtin_amdgcn_cvt_pk_f32_fp8(v1.x, false);
      acc[0] = fmaf(p[0], w1, acc[0]); acc[1] = fmaf(p[1], w1, acc[1]);
      p = __builtin_amdgcn_cvt_pk_f32_fp8(v1.x, true);
      acc[2] = fmaf(p[0], w1, acc[2]); acc[3] = fmaf(p[1], w1, acc[3]);
      p = __builtin_amdgcn_cvt_pk_f32_fp8(v1.y, false);
      acc[4] = fmaf(p[0], w1, acc[4]); acc[5] = fmaf(p[1], w1, acc[5]);
      p = __builtin_amdgcn_cvt_pk_f32_fp8(v1.y, true);
      acc[6] = fmaf(p[0], w1, acc[6]); acc[7] = fmaf(p[1], w1, acc[7]);

      p = __builtin_amdgcn_cvt_pk_f32_fp8(v2.x, false);
      acc[0] = fmaf(p[0], w2, acc[0]); acc[1] = fmaf(p[1], w2, acc[1]);
      p = __builtin_amdgcn_cvt_pk_f32_fp8(v2.x, true);
      acc[2] = fmaf(p[0], w2, acc[2]); acc[3] = fmaf(p[1], w2, acc[3]);
      p = __builtin_amdgcn_cvt_pk_f32_fp8(v2.y, false);
      acc[4] = fmaf(p[0], w2, acc[4]); acc[5] = fmaf(p[1], w2, acc[5]);
      p = __builtin_amdgcn_cvt_pk_f32_fp8(v2.y, true);
      acc[6] = fmaf(p[0], w2, acc[6]); acc[7] = fmaf(p[1], w2, acc[7]);

      p = __builtin_amdgcn_cvt_pk_f32_fp8(v3.x, false);
      acc[0] = fmaf(p[0], w3, acc[0]); acc[1] = fmaf(p[1], w3, acc[1]);
      p = __builtin_amdgcn_cvt_pk_f32_fp8(v3.x, true);
      acc[2] = fmaf(p[0], w3, acc[2]); acc[3] = fmaf(p[1], w3, acc[3]);
      p = __builtin_amdgcn_cvt_pk_f32_fp8(v3.y, false);
      acc[4] = fmaf(p[0], w3, acc[4]); acc[5] = fmaf(p[1], w3, acc[5]);
      p = __builtin_amdgcn_cvt_pk_f32_fp8(v3.y, true);
      acc[6] = fmaf(p[0], w3, acc[6]); acc[7] = fmaf(p[1], w3, acc[7]);
    }
  }

  // ---- LayerNorm over 128 cols, 8 per lane across 16 lanes ----
  int d0 = sl * 8;
  float4 bb0 = *(const float4*)(b + d0);
  float4 bb1 = *(const float4*)(b + d0 + 4);
  float a0 = acc[0] + bb0.x, a1 = acc[1] + bb0.y;
  float a2 = acc[2] + bb0.z, a3 = acc[3] + bb0.w;
  float a4 = acc[4] + bb1.x, a5 = acc[5] + bb1.y;
  float a6 = acc[6] + bb1.z, a7 = acc[7] + bb1.w;

  float sum = ((a0 + a1) + (a2 + a3)) + ((a4 + a5) + (a6 + a7));
#pragma unroll
  for (int o = 8; o >= 1; o >>= 1) sum += __shfl_xor(sum, o, 16);
  float mu = sum * (1.0f / 128.0f);
  float e0 = a0 - mu, e1 = a1 - mu, e2 = a2 - mu, e3 = a3 - mu;
  float e4 = a4 - mu, e5 = a5 - mu, e6 = a6 - mu, e7 = a7 - mu;
  float vs = ((e0 * e0 + e1 * e1) + (e2 * e2 + e3 * e3)) +
             ((e4 * e4 + e5 * e5) + (e6 * e6 + e7 * e7));
#pragma unroll
  for (int o = 8; o >= 1; o >>= 1) vs += __shfl_xor(vs, o, 16);
  float inv = rsqrtf(vs * (1.0f / 128.0f) + EPS);

  float4 gg0 = *(const float4*)(g + d0);
  float4 gg1 = *(const float4*)(g + d0 + 4);
  float4 bl0 = *(const float4*)(bln + d0);
  float4 bl1 = *(const float4*)(bln + d0 + 4);
  out[0] = fmaxf(e0 * inv * gg0.x + bl0.x, 0.0f);
  out[1] = fmaxf(e1 * inv * gg0.y + bl0.y, 0.0f);
  out[2] = fmaxf(e2 * inv * gg0.z + bl0.z, 0.0f);
  out[3] = fmaxf(e3 * inv * gg0.w + bl0.w, 0.0f);
  out[4] = fmaxf(e4 * inv * gg1.x + bl1.x, 0.0f);
  out[5] = fmaxf(e5 * inv * gg1.y + bl1.y, 0.0f);
  out[6] = fmaxf(e6 * inv * gg1.z + bl1.z, 0.0f);
  out[7] = fmaxf(e7 * inv * gg1.w + bl1.w, 0.0f);
}

// P6: fused gather1 + LN + ReLU -> LDS y1 (fp16) -> GEMM2 -> B (h2, fp8).
__global__ __launch_bounds__(256) void k_mid(
    const uint2* __restrict__ hb, const int4* __restrict__ meta,
    const u32* __restrict__ csr,
    const float* __restrict__ b, const float* __restrict__ g,
    const float* __restrict__ bln,
    const u16* __restrict__ Wt2, u8* __restrict__ outB, int n) {
  __shared__ alignas(16) u16 sY[64 * 136];
  const int tid = threadIdx.x;
  const int sl = tid & 15;
  const int row0 = blockIdx.x * 64;

  for (int p = 0; p < 4; p++) {
    int lr = p * 16 + (tid >> 4);
    int row = row0 + lr;
    float o[8];
    gather_ln_core(hb, meta, csr, b, g, bln, row, n, sl, o);
    uint4 pk;
    pk.x = ((u32)f2h(o[1]) << 16) | (u32)f2h(o[0]);
    pk.y = ((u32)f2h(o[3]) << 16) | (u32)f2h(o[2]);
    pk.z = ((u32)f2h(o[5]) << 16) | (u32)f2h(o[4]);
    pk.w = ((u32)f2h(o[7]) << 16) | (u32)f2h(o[6]);
    *(uint4*)(sY + lr * 136 + sl * 8) = pk;
  }
  __syncthreads();

  const int lane = tid & 63, wv = tid >> 6;
  const int m = lane & 15, q = lane >> 4;
  f32x4 acc[8];
#pragma unroll
  for (int ct = 0; ct < 8; ct++) acc[ct] = (f32x4)(0.0f);
  const u16* ap = sY + (wv * 16 + m) * 136 + q * 8;
#pragma unroll
  for (int kk = 0; kk < 4; kk++) {
    half8 a = *(const half8*)(ap + kk * 32);
#pragma unroll
    for (int ct = 0; ct < 8; ct++) {
      half8 bfr = *(const half8*)(Wt2 + (ct * 16 + m) * D + kk * 32 + q * 8);
      acc[ct] = __builtin_amdgcn_mfma_f32_16x16x32_f16(a, bfr, acc[ct], 0, 0, 0);
    }
  }
#pragma unroll
  for (int ct = 0; ct < 8; ct++) {
#pragma unroll
    for (int rg = 0; rg < 4; rg++) {
      int rr = row0 + wv * 16 + q * 4 + rg;
      if (rr < n) outB[(size_t)rr * D + ct * 16 + m] = f2fp8(acc[ct][rg]);
    }
  }
}

// P7: gather2 + LN + ReLU + residual -> fp32 out.
__global__ __launch_bounds__(256) void k_gather2(
    const uint2* __restrict__ hb, const int4* __restrict__ meta,
    const u32* __restrict__ csr,
    const float* __restrict__ b, const float* __restrict__ g,
    const float* __restrict__ bln, const float* __restrict__ resid,
    float* __restrict__ outf, int n) {
  const int tid = threadIdx.x;
  const int sl = tid & 15;
  const int row = blockIdx.x * 16 + (tid >> 4);
  float o[8];
  gather_ln_core(hb, meta, csr, b, g, bln, row, n, sl, o);
  if (row >= n) return;
  size_t base = (size_t)row * D + sl * 8;
  float4 r0 = *(const float4*)(resid + base);
  float4 r1 = *(const float4*)(resid + base + 4);
  *(float4*)(outf + base) =
      make_float4(o[0] + r0.x, o[1] + r0.y, o[2] + r0.z, o[3] + r0.w);
  *(float4*)(outf + base + 4) =
      make_float4(o[4] + r1.x, o[5] + r1.y, o[6] + r1.z, o[7] + r1.w);
}

// ---------------------------------------------------------------------------
extern "C" void kernel_launch(void* const* d_in, const int* in_sizes, int n_in,
                              void* d_out, int out_size, void* d_ws, size_t ws_size,
                              hipStream_t stream) {
  const float* x    = (const float*)d_in[0];
  const int*   ei   = (const int*)d_in[1];
  const float* W1   = (const float*)d_in[2];
  const float* b1   = (const float*)d_in[3];
  const float* g1   = (const float*)d_in[4];
  const float* bl1  = (const float*)d_in[5];
  const float* W2   = (const float*)d_in[6];
  const float* b2   = (const float*)d_in[7];
  const float* g2   = (const float*)d_in[8];
  const float* bl2  = (const float*)d_in[9];

  const int N = in_sizes[0] / D;
  const int E = in_sizes[1] / 2;
  const int* src = ei;
  const int* dst = ei + E;

  const int NB  = (N + BUCKW - 1) / BUCKW;  // coarse buckets
  const int M   = NB * KB;
  const int EPB = (E + KB - 1) / KB;        // edges per count/scatter block
  const int GB  = (N + 63) / 64;            // gemm/mid blocks

  size_t off = 0;
  auto walloc = [&](size_t bytes) {
    void* p = (char*)d_ws + off;
    off = (off + bytes + 255) & ~(size_t)255;
    return p;
  };
  int*   cnt   = (int*)walloc((size_t)M * 4);
  int*   bsv   = (int*)walloc((size_t)(NB + 1) * 4);
  u32*   tmp   = (u32*)walloc((size_t)E * 4);
  u32*   csr   = (u32*)walloc((size_t)E * 4);
  int4*  meta  = (int4*)walloc((size_t)N * 16);
  float* dinv  = (float*)walloc((size_t)N * 4);
  u8*    A     = (u8*)walloc((size_t)N * D);        // h1 (fp8 e4m3)
  u8*    B     = (u8*)walloc((size_t)N * D);        // h2 (fp8 e4m3)
  u16*   Wt1   = (u16*)walloc((size_t)D * D * 2);
  u16*   Wt2   = (u16*)walloc((size_t)D * D * 2);
  float* O     = (float*)d_out;

  // P0: weight converts
  k_prep<<<(2 * D * D + 255) / 256, 256, 0, stream>>>(W1, W2, Wt1, Wt2);
  // ph1: coarse count || GEMM1 (x @ W1 -> A fp8)
  k_count_gemm1<<<KB + GB, 256, 0, stream>>>(dst, cnt, E, NB, EPB, x, Wt1, A, N);
  // ph2: scan
  k_scan<<<1, 1024, 0, stream>>>(cnt, M, NB, bsv, E);
  // ph3: scatter into buckets
  k_scatter<<<KB, 256, 0, stream>>>(src, dst, cnt, tmp, E, NB, EPB);
  // ph4: per-bucket fine sort -> csr + meta + dinv
  k_bucket<<<NB, 256, 0, stream>>>(tmp, bsv, meta, dinv, csr, N);
  // ph5: pack weights
  k_weights<<<(N * 4 + 255) / 256, 256, 0, stream>>>(meta, dinv, csr, N);
  // P6: gather1 + LN + ReLU + GEMM2 -> B (fp8)
  k_mid<<<GB, 256, 0, stream>>>((const uint2*)A, meta, csr, b1, g1, bl1,
                                Wt2, B, N);
  // P7: gather2 + LN + ReLU + residual -> O
  k_gather2<<<(N + 15) / 16, 256, 0, stream>>>((const uint2*)B, meta, csr,
                                               b2, g2, bl2, x, O, N);
}